// Round 1
// baseline (220.262 us; speedup 1.0000x reference)
//
#include <hip/hip_runtime.h>
#include <math.h>

#define DD 512
#define KK 64
#define NN 4096
#define NSPLIT 8
#define EPSF 1e-12f

// ---------------------------------------------------------------------------
// Kernel A: scores = softmax_k(W @ desc + b)  ->  P [B][K][N]
// block: 256 threads = 128 n-positions x 2 k-halves. grid: B * N/128.
__global__ __launch_bounds__(256) void k_scores(const float* __restrict__ desc,
                                                const float* __restrict__ W,
                                                const float* __restrict__ bias,
                                                float* __restrict__ P) {
    const int bid = blockIdx.x;
    const int b   = bid >> 5;            // N/128 = 32 blocks per batch
    const int n0  = (bid & 31) << 7;
    const int t   = threadIdx.x;
    const int nl  = t & 127;
    const int kg  = t >> 7;              // 0/1 -> k in [kg*32, kg*32+32)
    const int n   = n0 + nl;

    __shared__ float Wl[64][68];         // [d_local][k], padded row
    __shared__ float red[2][128];

    float s[32];
#pragma unroll
    for (int j = 0; j < 32; ++j) s[j] = bias[kg * 32 + j];

    const float* dcol = desc + (size_t)b * DD * NN + n;

    for (int dt = 0; dt < DD / 64; ++dt) {
        // stage W tile: Wl[dl][k] = W[k][dt*64+dl]; coalesced float4 along d
        {
            const int k = t >> 2, q = t & 3;
#pragma unroll
            for (int i = 0; i < 4; ++i) {
                int dl = (q + 4 * i) * 4;
                float4 w = *(const float4*)&W[k * DD + dt * 64 + dl];
                Wl[dl + 0][k] = w.x;
                Wl[dl + 1][k] = w.y;
                Wl[dl + 2][k] = w.z;
                Wl[dl + 3][k] = w.w;
            }
        }
        __syncthreads();
        const float* dptr = dcol + (size_t)(dt * 64) * NN;
#pragma unroll 2
        for (int dl4 = 0; dl4 < 16; ++dl4) {
            float v0 = dptr[(size_t)(dl4 * 4 + 0) * NN];
            float v1 = dptr[(size_t)(dl4 * 4 + 1) * NN];
            float v2 = dptr[(size_t)(dl4 * 4 + 2) * NN];
            float v3 = dptr[(size_t)(dl4 * 4 + 3) * NN];
#pragma unroll
            for (int j4 = 0; j4 < 8; ++j4) {
                float4 w0 = *(const float4*)&Wl[dl4 * 4 + 0][kg * 32 + j4 * 4];
                float4 w1 = *(const float4*)&Wl[dl4 * 4 + 1][kg * 32 + j4 * 4];
                float4 w2 = *(const float4*)&Wl[dl4 * 4 + 2][kg * 32 + j4 * 4];
                float4 w3 = *(const float4*)&Wl[dl4 * 4 + 3][kg * 32 + j4 * 4];
                float a0 = s[j4 * 4 + 0], a1 = s[j4 * 4 + 1];
                float a2 = s[j4 * 4 + 2], a3 = s[j4 * 4 + 3];
                a0 = fmaf(w0.x, v0, a0); a1 = fmaf(w0.y, v0, a1);
                a2 = fmaf(w0.z, v0, a2); a3 = fmaf(w0.w, v0, a3);
                a0 = fmaf(w1.x, v1, a0); a1 = fmaf(w1.y, v1, a1);
                a2 = fmaf(w1.z, v1, a2); a3 = fmaf(w1.w, v1, a3);
                a0 = fmaf(w2.x, v2, a0); a1 = fmaf(w2.y, v2, a1);
                a2 = fmaf(w2.z, v2, a2); a3 = fmaf(w2.w, v2, a3);
                a0 = fmaf(w3.x, v3, a0); a1 = fmaf(w3.y, v3, a1);
                a2 = fmaf(w3.z, v3, a2); a3 = fmaf(w3.w, v3, a3);
                s[j4 * 4 + 0] = a0; s[j4 * 4 + 1] = a1;
                s[j4 * 4 + 2] = a2; s[j4 * 4 + 3] = a3;
            }
        }
        __syncthreads();
    }

    // softmax over 64 clusters (two 32-halves exchange via LDS)
    float m = s[0];
#pragma unroll
    for (int j = 1; j < 32; ++j) m = fmaxf(m, s[j]);
    red[kg][nl] = m;
    __syncthreads();
    float gm = fmaxf(red[0][nl], red[1][nl]);
    __syncthreads();
    float lsum = 0.f;
#pragma unroll
    for (int j = 0; j < 32; ++j) { s[j] = __expf(s[j] - gm); lsum += s[j]; }
    red[kg][nl] = lsum;
    __syncthreads();
    float inv = 1.0f / (red[0][nl] + red[1][nl]);

    float* prow = P + (size_t)(b * KK + kg * 32) * NN + n;
#pragma unroll
    for (int j = 0; j < 32; ++j) prow[(size_t)j * NN] = s[j] * inv;
}

// ---------------------------------------------------------------------------
// Kernel ssum: ssum[b][k] = sum_n P[b][k][n].  wave per row. grid: B*K/4.
__global__ __launch_bounds__(256) void k_ssum(const float* __restrict__ P,
                                              float* __restrict__ ssum) {
    const int w    = threadIdx.x >> 6;
    const int lane = threadIdx.x & 63;
    const int row  = blockIdx.x * 4 + w;    // b*K + k
    const float* pr = P + (size_t)row * NN;
    float acc = 0.f;
#pragma unroll
    for (int j = 0; j < 16; ++j) {
        float4 v = *(const float4*)&pr[j * 256 + lane * 4];
        acc += v.x + v.y + v.z + v.w;
    }
#pragma unroll
    for (int off = 32; off >= 1; off >>= 1) acc += __shfl_xor(acc, off, 64);
    if (lane == 0) ssum[row] = acc;
}

// ---------------------------------------------------------------------------
// Kernel B: partial agg.  block = (b, d-chunk of 64, n-slice of N/NSPLIT).
// part[ns][b][d][k] = sum_{n in slice} desc[b][d][n] * P[b][k][n]
__global__ __launch_bounds__(256) void k_agg(const float* __restrict__ desc,
                                             const float* __restrict__ P,
                                             float* __restrict__ part, int B) {
    const int bid = blockIdx.x;
    const int ns  = bid & (NSPLIT - 1);
    const int dc  = (bid >> 3) & 7;      // D/64 = 8 chunks
    const int b   = bid >> 6;
    const int t   = threadIdx.x;
    const int dt  = (t & 15) * 4;
    const int kt  = (t >> 4) * 4;

    __shared__ float Dt[64][68];
    __shared__ float Pt[64][68];

    float acc[16];
#pragma unroll
    for (int i = 0; i < 16; ++i) acc[i] = 0.f;

    const int rl = t >> 2, q = t & 3;
    for (int tile = 0; tile < (NN / NSPLIT) / 64; ++tile) {
        const int n0 = ns * (NN / NSPLIT) + tile * 64;
#pragma unroll
        for (int i = 0; i < 4; ++i) {
            int nl4 = (q + 4 * i) * 4;
            *(float4*)&Dt[rl][nl4] =
                *(const float4*)&desc[((size_t)b * DD + dc * 64 + rl) * NN + n0 + nl4];
            *(float4*)&Pt[rl][nl4] =
                *(const float4*)&P[((size_t)b * KK + rl) * NN + n0 + nl4];
        }
        __syncthreads();
#pragma unroll
        for (int g = 0; g < 16; ++g) {
            float4 dv[4], pv[4];
#pragma unroll
            for (int i = 0; i < 4; ++i) dv[i] = *(const float4*)&Dt[dt + i][g * 4];
#pragma unroll
            for (int j = 0; j < 4; ++j) pv[j] = *(const float4*)&Pt[kt + j][g * 4];
#pragma unroll
            for (int i = 0; i < 4; ++i)
#pragma unroll
                for (int j = 0; j < 4; ++j) {
                    float a = acc[i * 4 + j];
                    a = fmaf(dv[i].x, pv[j].x, a);
                    a = fmaf(dv[i].y, pv[j].y, a);
                    a = fmaf(dv[i].z, pv[j].z, a);
                    a = fmaf(dv[i].w, pv[j].w, a);
                    acc[i * 4 + j] = a;
                }
        }
        __syncthreads();
    }

#pragma unroll
    for (int i = 0; i < 4; ++i)
#pragma unroll
        for (int j = 0; j < 4; ++j)
            part[(((size_t)ns * B + b) * DD + dc * 64 + dt + i) * KK + kt + j] =
                acc[i * 4 + j];
}

// ---------------------------------------------------------------------------
// Reduce the NSPLIT partials -> agg [B][D][K]
__global__ __launch_bounds__(256) void k_reduce(const float* __restrict__ part,
                                                float* __restrict__ agg, int bdk) {
    size_t e = ((size_t)blockIdx.x * 256 + threadIdx.x) * 4;
    if (e >= (size_t)bdk) return;
    float4 a = *(const float4*)&part[e];
#pragma unroll
    for (int s = 1; s < NSPLIT; ++s) {
        float4 v = *(const float4*)&part[(size_t)s * bdk + e];
        a.x += v.x; a.y += v.y; a.z += v.z; a.w += v.w;
    }
    *(float4*)&agg[e] = a;
}

// ---------------------------------------------------------------------------
// Finalize: vlad = agg - centers*ssum; intra-norm over D; global L2 norm.
// block per batch, 256 threads = 64 k x 4 d-segments.
__global__ __launch_bounds__(256) void k_final(const float* __restrict__ agg,
                                               const float* __restrict__ centers,
                                               const float* __restrict__ ssum,
                                               float* __restrict__ out) {
    const int b = blockIdx.x;
    const int t = threadIdx.x;
    const int k = t & 63, seg = t >> 6;
    const float sm = ssum[b * KK + k];
    const float* ab = agg + (size_t)b * DD * KK;

    float sq = 0.f;
    for (int d = seg * 128; d < seg * 128 + 128; ++d) {
        float v = fmaf(-centers[d * KK + k], sm, ab[(size_t)d * KK + k]);
        sq = fmaf(v, v, sq);
    }
    __shared__ float red[4][64];
    __shared__ float cnc[64];
    __shared__ float gsh;
    red[seg][k] = sq;
    __syncthreads();
    if (seg == 0) {
        float cn2 = red[0][k] + red[1][k] + red[2][k] + red[3][k];
        float cn  = sqrtf(cn2);
        float c   = fmaxf(cn, EPSF);
        cnc[k]    = c;
        float tk  = cn2 / (c * c);
#pragma unroll
        for (int off = 32; off >= 1; off >>= 1) tk += __shfl_xor(tk, off, 64);
        if (k == 0) gsh = fmaxf(sqrtf(tk), EPSF);
    }
    __syncthreads();
    const float inv_g = 1.0f / gsh;
    const float inv_c = inv_g / cnc[k];
    float* ob = out + (size_t)b * DD * KK;
    for (int d = seg * 128; d < seg * 128 + 128; ++d) {
        float v = fmaf(-centers[d * KK + k], sm, ab[(size_t)d * KK + k]);
        ob[(size_t)d * KK + k] = v * inv_c;
    }
}

// ---------------------------------------------------------------------------
extern "C" void kernel_launch(void* const* d_in, const int* in_sizes, int n_in,
                              void* d_out, int out_size, void* d_ws, size_t ws_size,
                              hipStream_t stream) {
    const float* desc    = (const float*)d_in[0];
    const float* W       = (const float*)d_in[1];
    const float* bias    = (const float*)d_in[2];
    const float* centers = (const float*)d_in[3];
    float* out = (float*)d_out;

    const int B = in_sizes[0] / (DD * NN);   // 16
    const size_t pBytes    = (size_t)B * KK * NN * 4;          // 16.8 MB
    const size_t partBytes = (size_t)NSPLIT * B * DD * KK * 4; // 16.8 MB

    char* ws = (char*)d_ws;
    float* P    = (float*)ws;
    float* part = (float*)(ws + pBytes);
    float* agg  = (float*)(ws + pBytes + partBytes);
    float* ssum = agg + (size_t)B * DD * KK;

    k_scores<<<B * (NN / 128), 256, 0, stream>>>(desc, W, bias, P);
    k_ssum<<<B * KK / 4, 256, 0, stream>>>(P, ssum);
    k_agg<<<B * 8 * NSPLIT, 256, 0, stream>>>(desc, P, part, B);
    k_reduce<<<(B * DD * KK) / 1024, 256, 0, stream>>>(part, agg, B * DD * KK);
    k_final<<<B, 256, 0, stream>>>(agg, centers, ssum, out);
}

// Round 2
// 104.227 us; speedup vs baseline: 2.1133x; 2.1133x over previous
//
#include <hip/hip_runtime.h>
#include <hip/hip_bf16.h>
#include <math.h>

typedef __attribute__((ext_vector_type(8))) short short8;
typedef __attribute__((ext_vector_type(4))) float f32x4;
typedef __attribute__((ext_vector_type(4))) unsigned short u16x4;
typedef unsigned short u16;

#define DDIM 512
#define KCL 64
#define NPOS 4096
#define NSPL 8
#define EPSF 1e-12f

__device__ __forceinline__ u16 f2bf(float x) {
    __hip_bfloat16 h = __float2bfloat16(x);
    return __builtin_bit_cast(u16, h);
}
__device__ __forceinline__ float bf2f(u16 u) {
    unsigned i = ((unsigned)u) << 16;
    return __builtin_bit_cast(float, i);
}

// ---------------------------------------------------------------------------
// scores = softmax_k(W @ desc + b) -> P_hi/P_lo [B][N][K] bf16, pssum fp32
// grid (32 nblk, B), 256 thr. Split-bf16 MFMA: hh + lh + hl.
__global__ __launch_bounds__(256) void k_scores(const float* __restrict__ desc,
        const float* __restrict__ W, const float* __restrict__ bias,
        u16* __restrict__ Ph, u16* __restrict__ Pl, float* __restrict__ pssum) {
    const int nblk = blockIdx.x, b = blockIdx.y;
    const int t = threadIdx.x;
    const int w = t >> 6, lane = t & 63, c = lane & 15, g = lane >> 4;

    __shared__ u16 Wh[64][72], Wl[64][72];     // [k][d] pitch 72 (144B rows)
    __shared__ u16 Dh[64][130], Dl[64][130];   // [d][n] pitch 130

    f32x4 acc[4][2];
#pragma unroll
    for (int mf = 0; mf < 4; ++mf)
#pragma unroll
        for (int nf = 0; nf < 2; ++nf) acc[mf][nf] = (f32x4){0.f, 0.f, 0.f, 0.f};

    f32x4 bv[4];
#pragma unroll
    for (int mf = 0; mf < 4; ++mf)
        bv[mf] = *(const f32x4*)&bias[mf * 16 + g * 4];

    const int rl = t >> 2, q = t & 3;

    for (int dt = 0; dt < 8; ++dt) {
        const int d0 = dt * 64;
        // stage W tile [64k][64d] -> hi/lo
#pragma unroll
        for (int u = 0; u < 4; ++u) {
            const int dd = q * 16 + u * 4;
            float4 wv = *(const float4*)&W[(size_t)rl * DDIM + d0 + dd];
            u16 h0 = f2bf(wv.x), h1 = f2bf(wv.y), h2 = f2bf(wv.z), h3 = f2bf(wv.w);
            *(u16x4*)&Wh[rl][dd] = (u16x4){h0, h1, h2, h3};
            *(u16x4*)&Wl[rl][dd] = (u16x4){f2bf(wv.x - bf2f(h0)), f2bf(wv.y - bf2f(h1)),
                                           f2bf(wv.z - bf2f(h2)), f2bf(wv.w - bf2f(h3))};
        }
        // stage desc tile [64d][128n] -> hi/lo
        {
            const float* dsrc = desc + ((size_t)b * DDIM + d0 + rl) * NPOS + nblk * 128;
#pragma unroll
            for (int u = 0; u < 8; ++u) {
                const int n = q * 32 + u * 4;
                float4 dv = *(const float4*)&dsrc[n];
                u16 h0 = f2bf(dv.x), h1 = f2bf(dv.y), h2 = f2bf(dv.z), h3 = f2bf(dv.w);
                *(u16x4*)&Dh[rl][n] = (u16x4){h0, h1, h2, h3};
                *(u16x4*)&Dl[rl][n] = (u16x4){f2bf(dv.x - bf2f(h0)), f2bf(dv.y - bf2f(h1)),
                                              f2bf(dv.z - bf2f(h2)), f2bf(dv.w - bf2f(h3))};
            }
        }
        __syncthreads();
#pragma unroll
        for (int ks = 0; ks < 2; ++ks) {
            const int kk = ks * 32 + g * 8;
            short8 ah[4], al[4];
#pragma unroll
            for (int mf = 0; mf < 4; ++mf) {
                ah[mf] = *(const short8*)&Wh[mf * 16 + c][kk];
                al[mf] = *(const short8*)&Wl[mf * 16 + c][kk];
            }
#pragma unroll
            for (int nf = 0; nf < 2; ++nf) {
                const int nc = w * 32 + nf * 16 + c;
                short8 bh, bl;
#pragma unroll
                for (int j = 0; j < 8; ++j) {
                    bh[j] = (short)Dh[kk + j][nc];
                    bl[j] = (short)Dl[kk + j][nc];
                }
#pragma unroll
                for (int mf = 0; mf < 4; ++mf) {
                    acc[mf][nf] = __builtin_amdgcn_mfma_f32_16x16x32_bf16(ah[mf], bh, acc[mf][nf], 0, 0, 0);
                    acc[mf][nf] = __builtin_amdgcn_mfma_f32_16x16x32_bf16(al[mf], bh, acc[mf][nf], 0, 0, 0);
                    acc[mf][nf] = __builtin_amdgcn_mfma_f32_16x16x32_bf16(ah[mf], bl, acc[mf][nf], 0, 0, 0);
                }
            }
        }
        __syncthreads();
    }

    // epilogue: +bias, softmax over 64 k (own 16 + shfl_xor 16,32), split-store P
#pragma unroll
    for (int mf = 0; mf < 4; ++mf)
#pragma unroll
        for (int nf = 0; nf < 2; ++nf) acc[mf][nf] = acc[mf][nf] + bv[mf];

    float ps[4][4];
#pragma unroll
    for (int mf = 0; mf < 4; ++mf)
#pragma unroll
        for (int r = 0; r < 4; ++r) ps[mf][r] = 0.f;

#pragma unroll
    for (int nf = 0; nf < 2; ++nf) {
        float m = acc[0][nf][0];
#pragma unroll
        for (int mf = 0; mf < 4; ++mf)
#pragma unroll
            for (int r = 0; r < 4; ++r) m = fmaxf(m, acc[mf][nf][r]);
        m = fmaxf(m, __shfl_xor(m, 16));
        m = fmaxf(m, __shfl_xor(m, 32));
        float s = 0.f;
#pragma unroll
        for (int mf = 0; mf < 4; ++mf)
#pragma unroll
            for (int r = 0; r < 4; ++r) {
                float p = __expf(acc[mf][nf][r] - m);
                acc[mf][nf][r] = p;
                s += p;
            }
        s += __shfl_xor(s, 16);
        s += __shfl_xor(s, 32);
        const float inv = 1.0f / s;
        const size_t pbase = ((size_t)b * NPOS + nblk * 128 + w * 32 + nf * 16 + c) * KCL;
#pragma unroll
        for (int mf = 0; mf < 4; ++mf) {
            u16 h[4], l[4];
#pragma unroll
            for (int r = 0; r < 4; ++r) {
                float p = acc[mf][nf][r] * inv;
                ps[mf][r] += p;
                h[r] = f2bf(p);
                l[r] = f2bf(p - bf2f(h[r]));
            }
            *(u16x4*)&Ph[pbase + mf * 16 + g * 4] = (u16x4){h[0], h[1], h[2], h[3]};
            *(u16x4*)&Pl[pbase + mf * 16 + g * 4] = (u16x4){l[0], l[1], l[2], l[3]};
        }
    }
    // ssum partials: butterfly over the 16 c-lanes
#pragma unroll
    for (int mf = 0; mf < 4; ++mf)
#pragma unroll
        for (int r = 0; r < 4; ++r) {
            float v = ps[mf][r];
            v += __shfl_xor(v, 1);
            v += __shfl_xor(v, 2);
            v += __shfl_xor(v, 4);
            v += __shfl_xor(v, 8);
            ps[mf][r] = v;
        }
    if (c == 0) {
#pragma unroll
        for (int mf = 0; mf < 4; ++mf) {
            float4 o = make_float4(ps[mf][0], ps[mf][1], ps[mf][2], ps[mf][3]);
            *(float4*)&pssum[((size_t)b * 128 + nblk * 4 + w) * KCL + mf * 16 + g * 4] = o;
        }
    }
}

// ---------------------------------------------------------------------------
// part[ns][b][k][d] = sum_{n in slice} desc[b][d][n]*P[b][n][k]  (split-bf16)
// grid (4 dblk, 8 ns, B), 256 thr.
__global__ __launch_bounds__(256) void k_agg(const float* __restrict__ desc,
        const u16* __restrict__ Ph, const u16* __restrict__ Pl,
        float* __restrict__ part, int B) {
    const int dblk = blockIdx.x, ns = blockIdx.y, b = blockIdx.z;
    const int t = threadIdx.x;
    const int w = t >> 6, lane = t & 63, c = lane & 15, g = lane >> 4;
    const int wm = w & 1, wk = w >> 1;

    __shared__ u16 Ahs[128][72], Als[128][72];  // desc [d][n] pitch 72
    __shared__ u16 Bhs[64][66], Bls[64][66];    // P [n][k] pitch 66

    f32x4 acc[4][2];
#pragma unroll
    for (int mf = 0; mf < 4; ++mf)
#pragma unroll
        for (int nf = 0; nf < 2; ++nf) acc[mf][nf] = (f32x4){0.f, 0.f, 0.f, 0.f};

    const int rl = t >> 2, q = t & 3;

    for (int kt = 0; kt < 8; ++kt) {
        const int n0 = ns * 512 + kt * 64;
        // A: desc [128d][64n] -> hi/lo
#pragma unroll
        for (int rr = 0; rr < 2; ++rr) {
            const int row = rr * 64 + rl;
            const float* s = desc + ((size_t)b * DDIM + dblk * 128 + row) * NPOS + n0;
#pragma unroll
            for (int u = 0; u < 4; ++u) {
                const int n = q * 16 + u * 4;
                float4 dv = *(const float4*)&s[n];
                u16 h0 = f2bf(dv.x), h1 = f2bf(dv.y), h2 = f2bf(dv.z), h3 = f2bf(dv.w);
                *(u16x4*)&Ahs[row][n] = (u16x4){h0, h1, h2, h3};
                *(u16x4*)&Als[row][n] = (u16x4){f2bf(dv.x - bf2f(h0)), f2bf(dv.y - bf2f(h1)),
                                                f2bf(dv.z - bf2f(h2)), f2bf(dv.w - bf2f(h3))};
            }
        }
        // B: P tiles [64n][64k] (already bf16, scalar LDS writes into padded layout)
        {
            const size_t pb = ((size_t)b * NPOS + n0 + rl) * KCL + q * 16;
#pragma unroll
            for (int u = 0; u < 2; ++u) {
                short8 vh = *(const short8*)&Ph[pb + u * 8];
                short8 vl = *(const short8*)&Pl[pb + u * 8];
#pragma unroll
                for (int j = 0; j < 8; ++j) {
                    Bhs[rl][q * 16 + u * 8 + j] = (u16)vh[j];
                    Bls[rl][q * 16 + u * 8 + j] = (u16)vl[j];
                }
            }
        }
        __syncthreads();
#pragma unroll
        for (int ks = 0; ks < 2; ++ks) {
            const int kk = ks * 32 + g * 8;
            short8 ah[4], al[4];
#pragma unroll
            for (int mf = 0; mf < 4; ++mf) {
                ah[mf] = *(const short8*)&Ahs[wm * 64 + mf * 16 + c][kk];
                al[mf] = *(const short8*)&Als[wm * 64 + mf * 16 + c][kk];
            }
#pragma unroll
            for (int nf = 0; nf < 2; ++nf) {
                const int kc = wk * 32 + nf * 16 + c;
                short8 bh, bl;
#pragma unroll
                for (int j = 0; j < 8; ++j) {
                    bh[j] = (short)Bhs[kk + j][kc];
                    bl[j] = (short)Bls[kk + j][kc];
                }
#pragma unroll
                for (int mf = 0; mf < 4; ++mf) {
                    acc[mf][nf] = __builtin_amdgcn_mfma_f32_16x16x32_bf16(ah[mf], bh, acc[mf][nf], 0, 0, 0);
                    acc[mf][nf] = __builtin_amdgcn_mfma_f32_16x16x32_bf16(al[mf], bh, acc[mf][nf], 0, 0, 0);
                    acc[mf][nf] = __builtin_amdgcn_mfma_f32_16x16x32_bf16(ah[mf], bl, acc[mf][nf], 0, 0, 0);
                }
            }
        }
        __syncthreads();
    }
    // C[row=d][col=k]: 4 consecutive d per lane -> float4 into part[ns][b][k][d]
#pragma unroll
    for (int nf = 0; nf < 2; ++nf) {
        const int k = wk * 32 + nf * 16 + c;
#pragma unroll
        for (int mf = 0; mf < 4; ++mf) {
            float4 o = make_float4(acc[mf][nf][0], acc[mf][nf][1], acc[mf][nf][2], acc[mf][nf][3]);
            *(float4*)&part[(((size_t)ns * B + b) * KCL + k) * DDIM + dblk * 128 + wm * 64 + mf * 16 + g * 4] = o;
        }
    }
}

// ---------------------------------------------------------------------------
__global__ __launch_bounds__(256) void k_reduce(const float* __restrict__ part,
                                                float* __restrict__ agg, int bkd) {
    size_t e = ((size_t)blockIdx.x * 256 + threadIdx.x) * 4;
    if (e >= (size_t)bkd) return;
    float4 a = *(const float4*)&part[e];
#pragma unroll
    for (int s = 1; s < NSPL; ++s) {
        float4 v = *(const float4*)&part[(size_t)s * bkd + e];
        a.x += v.x; a.y += v.y; a.z += v.z; a.w += v.w;
    }
    *(float4*)&agg[e] = a;
}

// centersT[k][d] <- centers[d][k]
__global__ __launch_bounds__(256) void k_centersT(const float* __restrict__ cen,
                                                  float* __restrict__ cT) {
    __shared__ float L[64][65];
    const int dc = blockIdx.x, t = threadIdx.x, r = t >> 2, q = t & 3;
#pragma unroll
    for (int u = 0; u < 4; ++u) {
        const int k = q * 16 + u * 4;
        float4 v = *(const float4*)&cen[((size_t)dc * 64 + r) * KCL + k];
        L[r][k] = v.x; L[r][k + 1] = v.y; L[r][k + 2] = v.z; L[r][k + 3] = v.w;
    }
    __syncthreads();
#pragma unroll
    for (int u = 0; u < 4; ++u) {
        const int d = q * 16 + u * 4;
        float4 o = make_float4(L[d][r], L[d + 1][r], L[d + 2][r], L[d + 3][r]);
        *(float4*)&cT[(size_t)r * DDIM + dc * 64 + d] = o;
    }
}

__global__ void k_mid(const float* __restrict__ pssum, float* __restrict__ ssum) {
    const int b = blockIdx.x, k = threadIdx.x;
    float a = 0.f;
    for (int nw = 0; nw < 128; ++nw) a += pssum[((size_t)b * 128 + nw) * KCL + k];
    ssum[b * KCL + k] = a;
}

// per-(b,k) column norms on v = agg - cT*ssum; invc = 1/(gn * clamp(cn))
__global__ __launch_bounds__(256) void k_norms(const float* __restrict__ agg,
        const float* __restrict__ cT, const float* __restrict__ ssum,
        float* __restrict__ invc) {
    const int b = blockIdx.x, t = threadIdx.x, w = t >> 6, lane = t & 63;
    __shared__ float cc[64], gp[4];
    float gacc = 0.f;
    for (int i = 0; i < 16; ++i) {
        const int k = w * 16 + i;
        const float sm = ssum[b * KCL + k];
        const float* ar = agg + ((size_t)b * KCL + k) * DDIM + lane * 8;
        const float* cr = cT + (size_t)k * DDIM + lane * 8;
        float sq = 0.f;
#pragma unroll
        for (int j = 0; j < 8; ++j) {
            float v = fmaf(-cr[j], sm, ar[j]);
            sq = fmaf(v, v, sq);
        }
#pragma unroll
        for (int off = 32; off >= 1; off >>= 1) sq += __shfl_xor(sq, off);
        float cl = fmaxf(sqrtf(sq), EPSF);
        if (lane == 0) cc[k] = cl;
        gacc += sq / (cl * cl);
    }
    if (lane == 0) gp[w] = gacc;
    __syncthreads();
    if (t < 64) {
        float gn = fmaxf(sqrtf(gp[0] + gp[1] + gp[2] + gp[3]), EPSF);
        invc[b * KCL + t] = 1.0f / (gn * cc[t]);
    }
}

// out[b][d][k] = (agg[b][k][d] - cT[k][d]*ssum) * invc[b][k]  (LDS transpose)
__global__ __launch_bounds__(256) void k_out(const float* __restrict__ agg,
        const float* __restrict__ cT, const float* __restrict__ ssum,
        const float* __restrict__ invc, float* __restrict__ out) {
    const int dc = blockIdx.x, b = blockIdx.y;
    const int t = threadIdx.x, r = t >> 2, q = t & 3;
    __shared__ float L[64][65];
    const float sm = ssum[b * KCL + r], ic = invc[b * KCL + r];
#pragma unroll
    for (int u = 0; u < 4; ++u) {
        const int d = q * 16 + u * 4;
        float4 a = *(const float4*)&agg[((size_t)b * KCL + r) * DDIM + dc * 64 + d];
        float4 cv = *(const float4*)&cT[(size_t)r * DDIM + dc * 64 + d];
        L[r][d]     = fmaf(-cv.x, sm, a.x) * ic;
        L[r][d + 1] = fmaf(-cv.y, sm, a.y) * ic;
        L[r][d + 2] = fmaf(-cv.z, sm, a.z) * ic;
        L[r][d + 3] = fmaf(-cv.w, sm, a.w) * ic;
    }
    __syncthreads();
#pragma unroll
    for (int u = 0; u < 4; ++u) {
        const int k = q * 16 + u * 4;
        float4 o = make_float4(L[k][r], L[k + 1][r], L[k + 2][r], L[k + 3][r]);
        *(float4*)&out[((size_t)b * DDIM + dc * 64 + r) * KCL + k] = o;
    }
}

// ---------------------------------------------------------------------------
extern "C" void kernel_launch(void* const* d_in, const int* in_sizes, int n_in,
                              void* d_out, int out_size, void* d_ws, size_t ws_size,
                              hipStream_t stream) {
    const float* desc    = (const float*)d_in[0];
    const float* W       = (const float*)d_in[1];
    const float* bias    = (const float*)d_in[2];
    const float* centers = (const float*)d_in[3];
    float* out = (float*)d_out;

    const int B = in_sizes[0] / (DDIM * NPOS);  // 16

    char* ws = (char*)d_ws;
    const size_t pPlane = (size_t)B * NPOS * KCL * 2;           // 8.39 MB
    const size_t partSz = (size_t)NSPL * B * KCL * DDIM * 4;    // 16.78 MB
    u16*   Ph    = (u16*)ws;
    u16*   Pl    = (u16*)(ws + pPlane);
    float* part  = (float*)(ws + 2 * pPlane);
    float* pssum = part;  // aliased: consumed by k_mid before k_agg writes part
    float* agg   = (float*)(ws + 2 * pPlane + partSz);
    float* cT    = agg + (size_t)B * KCL * DDIM;
    float* ssum  = cT + (size_t)KCL * DDIM;
    float* invc  = ssum + B * KCL;

    k_centersT<<<8, 256, 0, stream>>>(centers, cT);
    k_scores<<<dim3(NPOS / 128, B), 256, 0, stream>>>(desc, W, bias, Ph, Pl, pssum);
    k_mid<<<B, 64, 0, stream>>>(pssum, ssum);
    k_agg<<<dim3(4, NSPL, B), 256, 0, stream>>>(desc, Ph, Pl, part, B);
    k_reduce<<<(B * KCL * DDIM) / 1024, 256, 0, stream>>>(part, agg, B * KCL * DDIM);
    k_norms<<<B, 256, 0, stream>>>(agg, cT, ssum, invc);
    k_out<<<dim3(8, B), 256, 0, stream>>>(agg, cT, ssum, invc, out);
}